// Round 11
// baseline (975.079 us; speedup 1.0000x reference)
//
#include <hip/hip_runtime.h>

static constexpr int NN = 1000000;
static constexpr int NE = 16000000;
static constexpr int BSH = 11;                  // 2048-node buckets
static constexpr int BNODES = 1 << BSH;
static constexpr int BMASK = BNODES - 1;
static constexpr int NB = (NN + BMASK) >> BSH;  // 489 buckets
static constexpr int CAPB = 40960;              // bucket slot capacity (45 sigma)
static constexpr int NWG = 256;                 // binning workgroups (1/CU)
static constexpr int EPW = NE / NWG;            // 62500 edges per wg
static constexpr int CHUNK = 16;                // flush granularity (64 B)
static constexpr int CAP = 24;                  // staging capacity per bucket
static constexpr int KE = 4;                    // edges per thread per round

// ---------- init: lo = 0, hi = CAPB ----------

__global__ void k_init(int* __restrict__ lo, int* __restrict__ hi) {
    int i = blockIdx.x * blockDim.x + threadIdx.x;
    if (i < NB) { lo[i] = 0; hi[i] = CAPB; }
}

// ---------- build: write-combined binning with global chunk cursors ----------
// entry = (row << 11) | (col & 2047). Full 16-entry chunks reserve 16-aligned
// space at the LOW end (uint4 stores); remainders/overflow dribble from the
// HIGH end so low-end 16B alignment is never broken.

__global__ __launch_bounds__(512) void k_bin3(const int* __restrict__ row,
                                              const int* __restrict__ col,
                                              int* __restrict__ lo_g,
                                              int* __restrict__ hi_g,
                                              unsigned* __restrict__ binned) {
    __shared__ unsigned stage[NB][CAP];  // ~47 KB
    __shared__ int scnt[NB];
    int w = blockIdx.x;
    for (int i = threadIdx.x; i < NB; i += 512) scnt[i] = 0;
    __syncthreads();
    long long e0 = (long long)w * EPW;
    long long e1 = e0 + EPW; if (e1 > NE) e1 = NE;
    const int TILE = 512 * KE;
    for (long long t0 = e0; t0 < e1; t0 += TILE) {
        int cs[KE], rs[KE];
        bool ok[KE];
#pragma unroll
        for (int k = 0; k < KE; ++k) {
            long long e = t0 + k * 512 + threadIdx.x;
            ok[k] = (e < e1);
            cs[k] = ok[k] ? col[e] : 0;
            rs[k] = ok[k] ? row[e] : 0;
        }
#pragma unroll
        for (int k = 0; k < KE; ++k) {
            if (ok[k]) {
                int b = cs[k] >> BSH;
                unsigned v = ((unsigned)rs[k] << BSH) | (unsigned)(cs[k] & BMASK);
                int s = atomicAdd(&scnt[b], 1);
                if (s < CAP) stage[b][s] = v;
                else {  // rare overflow -> high-end dribble
                    int p = atomicSub(&hi_g[b], 1) - 1;
                    binned[(long long)b * CAPB + p] = v;
                }
            }
        }
        __syncthreads();
        for (int b = threadIdx.x; b < NB; b += 512) {
            int n = scnt[b]; if (n > CAP) n = CAP;
            if (n >= CHUNK) {
                int p = atomicAdd(&lo_g[b], CHUNK);
                uint4* src = (uint4*)&stage[b][0];
                uint4* dst = (uint4*)(binned + (long long)b * CAPB + p);
                dst[0] = src[0]; dst[1] = src[1]; dst[2] = src[2]; dst[3] = src[3];
                int rem = n - CHUNK;
                for (int q = 0; q < rem; ++q) stage[b][q] = stage[b][CHUNK + q];
                scnt[b] = rem;
            } else {
                scnt[b] = n;
            }
        }
        __syncthreads();
    }
    // epilogue: flush leftovers (full chunk if present, then high-end dribble)
    for (int b = threadIdx.x; b < NB; b += 512) {
        int n = scnt[b]; if (n > CAP) n = CAP;
        int q = 0;
        if (n >= CHUNK) {
            int p = atomicAdd(&lo_g[b], CHUNK);
            uint4* src = (uint4*)&stage[b][0];
            uint4* dst = (uint4*)(binned + (long long)b * CAPB + p);
            dst[0] = src[0]; dst[1] = src[1]; dst[2] = src[2]; dst[3] = src[3];
            q = CHUNK;
        }
        int rem = n - q;
        if (rem > 0) {
            int p = atomicSub(&hi_g[b], rem) - rem;
            for (int i = 0; i < rem; ++i)
                binned[(long long)b * CAPB + p + i] = stage[b][q + i];
        }
    }
}

// ---------- scan bucket sizes -> bucketBase ----------

__global__ void k_bbase(const int* __restrict__ lo_g, const int* __restrict__ hi_g,
                        int* __restrict__ bucketBase, int* __restrict__ ptr) {
    __shared__ int sm[512];
    int t = threadIdx.x;
    int v = (t < NB) ? (lo_g[t] + (CAPB - hi_g[t])) : 0;
    sm[t] = v;
    __syncthreads();
    for (int off = 1; off < 512; off <<= 1) {
        int x = (t >= off) ? sm[t - off] : 0;
        __syncthreads();
        sm[t] += x;
        __syncthreads();
    }
    if (t < NB) bucketBase[t] = sm[t] - v;
    if (t == 0) { bucketBase[NB] = NE; ptr[NN] = NE; }
}

// ---------- fused: histogram + scan -> ptr, dis; then scatter ----------

__global__ __launch_bounds__(512) void k_sort(const unsigned* __restrict__ binned,
                                              const int* __restrict__ lo_g,
                                              const int* __restrict__ hi_g,
                                              const int* __restrict__ bucketBase,
                                              int* __restrict__ ptr,
                                              float* __restrict__ dis,
                                              int* __restrict__ sortedRow) {
    __shared__ int cnt[BNODES];  // 8 KB: histogram, then cursors
    __shared__ int tsum[512];
    int b = blockIdx.x, t = threadIdx.x;
    for (int i = t; i < BNODES; i += 512) cnt[i] = 0;
    __syncthreads();
    long long B0 = (long long)b * CAPB;
    int loN = lo_g[b], hiN = hi_g[b];
    // range A: [B0, B0+loN), range B: [B0+hiN, B0+CAPB)
    {
        long long i = B0 + t;
        long long iA = B0 + loN;
        for (; i + 3584 < iA; i += 4096) {
            unsigned v0 = binned[i],        v1 = binned[i +  512];
            unsigned v2 = binned[i + 1024], v3 = binned[i + 1536];
            unsigned v4 = binned[i + 2048], v5 = binned[i + 2560];
            unsigned v6 = binned[i + 3072], v7 = binned[i + 3584];
            atomicAdd(&cnt[v0 & BMASK], 1);
            atomicAdd(&cnt[v1 & BMASK], 1);
            atomicAdd(&cnt[v2 & BMASK], 1);
            atomicAdd(&cnt[v3 & BMASK], 1);
            atomicAdd(&cnt[v4 & BMASK], 1);
            atomicAdd(&cnt[v5 & BMASK], 1);
            atomicAdd(&cnt[v6 & BMASK], 1);
            atomicAdd(&cnt[v7 & BMASK], 1);
        }
        for (; i < iA; i += 512) atomicAdd(&cnt[binned[i] & BMASK], 1);
        for (long long j = B0 + hiN + t; j < B0 + CAPB; j += 512)
            atomicAdd(&cnt[binned[j] & BMASK], 1);
    }
    __syncthreads();
    int s0 = cnt[t * 4], s1 = cnt[t * 4 + 1], s2 = cnt[t * 4 + 2], s3 = cnt[t * 4 + 3];
    int tot = s0 + s1 + s2 + s3;
    tsum[t] = tot;
    __syncthreads();
    for (int off = 1; off < 512; off <<= 1) {
        int x = (t >= off) ? tsum[t - off] : 0;
        __syncthreads();
        tsum[t] += x;
        __syncthreads();
    }
    int base = bucketBase[b] + tsum[t] - tot;  // exclusive start for node t*4
    int n0 = (b << BSH) + t * 4;
    if (n0 < NN)     { ptr[n0]     = base;                dis[n0]     = rsqrtf((float)(s0 + 1)); }
    if (n0 + 1 < NN) { ptr[n0 + 1] = base + s0;           dis[n0 + 1] = rsqrtf((float)(s1 + 1)); }
    if (n0 + 2 < NN) { ptr[n0 + 2] = base + s0 + s1;      dis[n0 + 2] = rsqrtf((float)(s2 + 1)); }
    if (n0 + 3 < NN) { ptr[n0 + 3] = base + s0 + s1 + s2; dis[n0 + 3] = rsqrtf((float)(s3 + 1)); }
    __syncthreads();
    cnt[t * 4]     = base;
    cnt[t * 4 + 1] = base + s0;
    cnt[t * 4 + 2] = base + s0 + s1;
    cnt[t * 4 + 3] = base + s0 + s1 + s2;
    __syncthreads();
    {
        long long i = B0 + t;
        long long iA = B0 + loN;
        for (; i + 3584 < iA; i += 4096) {
            unsigned v0 = binned[i],        v1 = binned[i +  512];
            unsigned v2 = binned[i + 1024], v3 = binned[i + 1536];
            unsigned v4 = binned[i + 2048], v5 = binned[i + 2560];
            unsigned v6 = binned[i + 3072], v7 = binned[i + 3584];
            int p0 = atomicAdd(&cnt[v0 & BMASK], 1);
            int p1 = atomicAdd(&cnt[v1 & BMASK], 1);
            int p2 = atomicAdd(&cnt[v2 & BMASK], 1);
            int p3 = atomicAdd(&cnt[v3 & BMASK], 1);
            int p4 = atomicAdd(&cnt[v4 & BMASK], 1);
            int p5 = atomicAdd(&cnt[v5 & BMASK], 1);
            int p6 = atomicAdd(&cnt[v6 & BMASK], 1);
            int p7 = atomicAdd(&cnt[v7 & BMASK], 1);
            sortedRow[p0] = (int)(v0 >> BSH);
            sortedRow[p1] = (int)(v1 >> BSH);
            sortedRow[p2] = (int)(v2 >> BSH);
            sortedRow[p3] = (int)(v3 >> BSH);
            sortedRow[p4] = (int)(v4 >> BSH);
            sortedRow[p5] = (int)(v5 >> BSH);
            sortedRow[p6] = (int)(v6 >> BSH);
            sortedRow[p7] = (int)(v7 >> BSH);
        }
        for (; i < iA; i += 512) {
            unsigned v = binned[i];
            int pos = atomicAdd(&cnt[v & BMASK], 1);
            sortedRow[pos] = (int)(v >> BSH);
        }
        for (long long j = B0 + hiN + t; j < B0 + CAPB; j += 512) {
            unsigned v = binned[j];
            int pos = atomicAdd(&cnt[v & BMASK], 1);
            sortedRow[pos] = (int)(v >> BSH);
        }
    }
}

// ---------- layer 1 linear: g1 = (x @ W1) * dis, LDS-staged coalesced x ------

__global__ __launch_bounds__(256) void k_lin1(const float* __restrict__ x,
                                              const float* __restrict__ W1,
                                              const float* __restrict__ dis,
                                              float* __restrict__ g1) {
    __shared__ float w[144];   // 9x16
    __shared__ float xs[2304]; // 256 nodes x 9 feats
    int t = threadIdx.x;
    if (t < 144) w[t] = W1[t];
    long long f4base = (long long)blockIdx.x * 576;  // block tile = 576 float4
    const float4* xv = (const float4*)x;
#pragma unroll
    for (int i = 0; i < 3; ++i) {
        int idx = t + i * 256;
        if (idx < 576 && f4base + idx < (long long)NN * 9 / 4)
            ((float4*)xs)[idx] = xv[f4base + idx];
    }
    __syncthreads();
    int n = blockIdx.x * 256 + t;
    if (n >= NN) return;
    float xvr[9];
#pragma unroll
    for (int k = 0; k < 9; ++k) xvr[k] = xs[t * 9 + k];
    float d = dis[n];
    float o[16];
#pragma unroll
    for (int j = 0; j < 16; ++j) {
        float acc = 0.f;
#pragma unroll
        for (int k = 0; k < 9; ++k) acc = fmaf(xvr[k], w[k * 16 + j], acc);
        o[j] = acc * d;
    }
    float4* dst = (float4*)(g1 + (long long)n * 16);
    dst[0] = make_float4(o[0], o[1], o[2], o[3]);
    dst[1] = make_float4(o[4], o[5], o[6], o[7]);
    dst[2] = make_float4(o[8], o[9], o[10], o[11]);
    dst[3] = make_float4(o[12], o[13], o[14], o[15]);
}

// ---------- fused pulls (proven round-8 form, untouched) ----------
// MODE 0: writeout fuses layer-2 linear: g2 = (relu(dis*acc + b1) @ W2pad) * dis
// MODE 1: writeout fuses final projection: out[n] = sum_j (dis*acc + b2)_j Wf_j + bf

template <int MODE>
__global__ void k_pull_f(const int* __restrict__ ptr, const int* __restrict__ sortedRow,
                         const float* __restrict__ dis, const float* __restrict__ g,
                         const float* __restrict__ p0, const float* __restrict__ p1,
                         const float* __restrict__ p2, float* __restrict__ dst) {
    __shared__ float w2s[256];  // MODE0: W2 padded [16][16]
    __shared__ float c16[16];   // MODE0: b1 | MODE1: b2 padded
    __shared__ float wf16[16];  // MODE1: Wf padded
    __shared__ float bfs;
    if (MODE == 0) {
        if (threadIdx.x < 256) {
            int k = threadIdx.x >> 4, j = threadIdx.x & 15;
            w2s[threadIdx.x] = (j < 10) ? p1[k * 10 + j] : 0.f;  // p1 = W2
        }
        if (threadIdx.x < 16) c16[threadIdx.x] = p0[threadIdx.x];  // p0 = b1 (16)
    } else {
        if (threadIdx.x < 16) {
            c16[threadIdx.x]  = (threadIdx.x < 10) ? p0[threadIdx.x] : 0.f;  // b2
            wf16[threadIdx.x] = (threadIdx.x < 10) ? p1[threadIdx.x] : 0.f;  // Wf
        }
        if (threadIdx.x == 0) bfs = p2[0];
    }
    __syncthreads();

    int grp = threadIdx.x >> 4;
    int j = threadIdx.x & 15;
    int n = blockIdx.x * 16 + grp;
    if (n >= NN) return;
    int e0 = ptr[n], e1 = ptr[n + 1];
    float acc = g[(long long)n * 16 + j];  // self-loop term
    int e = e0;
    for (; e + 16 <= e1; e += 16) {
        int r[16];
#pragma unroll
        for (int k = 0; k < 16; ++k) r[k] = sortedRow[e + k];
        float v[16];
#pragma unroll
        for (int k = 0; k < 16; ++k) v[k] = g[(long long)r[k] * 16 + j];
        float s0 = ((v[0] + v[1]) + (v[2] + v[3])) + ((v[4] + v[5]) + (v[6] + v[7]));
        float s1 = ((v[8] + v[9]) + (v[10] + v[11])) + ((v[12] + v[13]) + (v[14] + v[15]));
        acc += s0 + s1;
    }
    for (; e + 4 <= e1; e += 4) {
        int r0 = sortedRow[e + 0], r1 = sortedRow[e + 1];
        int r2 = sortedRow[e + 2], r3 = sortedRow[e + 3];
        float v0 = g[(long long)r0 * 16 + j];
        float v1 = g[(long long)r1 * 16 + j];
        float v2 = g[(long long)r2 * 16 + j];
        float v3 = g[(long long)r3 * 16 + j];
        acc += (v0 + v1) + (v2 + v3);
    }
    for (; e < e1; ++e)
        acc += g[(long long)sortedRow[e] * 16 + j];

    float d = dis[n];
    float val = d * acc;
    if (MODE == 0) {
        float hv = fmaxf(val + c16[j], 0.f);
        float o = 0.f;
#pragma unroll
        for (int k = 0; k < 16; ++k)
            o = fmaf(__shfl(hv, k, 16), w2s[k * 16 + j], o);
        dst[(long long)n * 16 + j] = o * d;
    } else {
        float t = (val + c16[j]) * wf16[j];
#pragma unroll
        for (int m = 8; m >= 1; m >>= 1) t += __shfl_xor(t, m, 16);
        if (j == 0) dst[n] = t + bfs;
    }
}

extern "C" void kernel_launch(void* const* d_in, const int* in_sizes, int n_in,
                              void* d_out, int out_size, void* d_ws, size_t ws_size,
                              hipStream_t stream) {
    const float* x  = (const float*)d_in[0];
    const int*   ei = (const int*)d_in[1];
    const float* W1 = (const float*)d_in[2];
    const float* b1 = (const float*)d_in[3];
    const float* W2 = (const float*)d_in[4];
    const float* b2 = (const float*)d_in[5];
    const float* Wf = (const float*)d_in[6];
    const float* bf = (const float*)d_in[7];
    float* out = (float*)d_out;

    const int* row = ei;
    const int* col = ei + NE;

    char* ws = (char*)d_ws;
    size_t off = 0;
    auto alloc = [&](size_t bytes) -> void* {
        void* p = ws + off;
        off += (bytes + 255) & ~255ULL;
        return p;
    };
    int* lo_g        = (int*)alloc((size_t)NB * 4);
    int* hi_g        = (int*)alloc((size_t)NB * 4);
    int* bucketBase  = (int*)alloc((size_t)(NB + 1) * 4);
    int* ptr         = (int*)alloc((size_t)(NN + 1) * 4);
    float* dis       = (float*)alloc((size_t)NN * 4);
    unsigned* binned = (unsigned*)alloc((size_t)NB * CAPB * 4);  // 80 MB; reused as g2
    int* sortedRow   = (int*)alloc((size_t)NE * 4);              // 64 MB
    float* g1        = (float*)alloc((size_t)NN * 16 * 4);       // 64 MB

    float* g2 = (float*)binned;  // binned dead after k_sort

    const int TB = 256;
    const int nodeGrid = (NN + TB - 1) / TB;
    const int pullGrid = (NN + 15) / 16;

    k_init<<<(NB + 255) / 256, 256, 0, stream>>>(lo_g, hi_g);
    k_bin3<<<NWG, 512, 0, stream>>>(row, col, lo_g, hi_g, binned);
    k_bbase<<<1, 512, 0, stream>>>(lo_g, hi_g, bucketBase, ptr);
    k_sort<<<NB, 512, 0, stream>>>(binned, lo_g, hi_g, bucketBase, ptr, dis, sortedRow);

    k_lin1<<<nodeGrid, TB, 0, stream>>>(x, W1, dis, g1);
    k_pull_f<0><<<pullGrid, TB, 0, stream>>>(ptr, sortedRow, dis, g1, b1, W2, nullptr, g2);
    k_pull_f<1><<<pullGrid, TB, 0, stream>>>(ptr, sortedRow, dis, g2, b2, Wf, bf, out);
}

// Round 12
// 876.155 us; speedup vs baseline: 1.1129x; 1.1129x over previous
//
#include <hip/hip_runtime.h>

static constexpr int NN = 1000000;
static constexpr int NE = 16000000;
static constexpr int BSH = 11;                  // 2048-node buckets
static constexpr int BNODES = 1 << BSH;
static constexpr int BMASK = BNODES - 1;
static constexpr int NB = (NN + BMASK) >> BSH;  // 489 buckets
static constexpr int NWG = 500;                 // binning workgroups (EPW 16B-aligned)
static constexpr int EPW = NE / NWG;            // 32000 edges per wg (div by 4)
static constexpr int CHUNK = 16;                // flush granularity (64 B)
static constexpr int CAP = 24;                  // staging capacity per bucket

// ---------- build A: per-(bucket, wg) counts — int4 loads, 4-way replicated ----

__global__ __launch_bounds__(512) void k_count(const int* __restrict__ col,
                                               int* __restrict__ counts) {
    __shared__ int cnt[4][NB];
    for (int i = threadIdx.x; i < 4 * NB; i += 512) ((int*)cnt)[i] = 0;
    __syncthreads();
    int w = blockIdx.x;
    int rep = threadIdx.x & 3;
    const int4* col4 = (const int4*)(col + (long long)w * EPW);
    const int nq = EPW / 4;  // 8000
    for (int q = threadIdx.x; q < nq; q += 512) {
        int4 c = col4[q];
        atomicAdd(&cnt[rep][c.x >> BSH], 1);
        atomicAdd(&cnt[rep][c.y >> BSH], 1);
        atomicAdd(&cnt[rep][c.z >> BSH], 1);
        atomicAdd(&cnt[rep][c.w >> BSH], 1);
    }
    __syncthreads();
    for (int i = threadIdx.x; i < NB; i += 512)
        counts[i * NWG + w] = cnt[0][i] + cnt[1][i] + cnt[2][i] + cnt[3][i];
}

// ---------- build B1: per-bucket exclusive scan over wgs (in place) ----------

__global__ __launch_bounds__(512) void k_scan_wg(int* __restrict__ counts,
                                                 int* __restrict__ bucketTotal) {
    __shared__ int sm[512];
    int b = blockIdx.x, t = threadIdx.x;
    int v = (t < NWG) ? counts[b * NWG + t] : 0;
    sm[t] = v;
    __syncthreads();
    for (int off = 1; off < 512; off <<= 1) {
        int x = (t >= off) ? sm[t - off] : 0;
        __syncthreads();
        sm[t] += x;
        __syncthreads();
    }
    if (t < NWG) counts[b * NWG + t] = sm[t] - v;  // exclusive prefix within bucket
    if (t == 511) bucketTotal[b] = sm[511];
}

// ---------- build B2: exclusive scan of bucket totals; also ptr[NN]=NE ------

__global__ void k_scan_total(const int* __restrict__ bucketTotal,
                             int* __restrict__ bucketBase, int* __restrict__ ptr) {
    __shared__ int sm[512];
    int t = threadIdx.x;
    int v = (t < NB) ? bucketTotal[t] : 0;
    sm[t] = v;
    __syncthreads();
    for (int off = 1; off < 512; off <<= 1) {
        int x = (t >= off) ? sm[t - off] : 0;
        __syncthreads();
        sm[t] += x;
        __syncthreads();
    }
    if (t < NB) bucketBase[t] = sm[t] - v;
    if (t == 0) { bucketBase[NB] = NE; ptr[NN] = NE; }
}

// ---------- build C: write-combined binning, int4 loads ----------
// entry = (row << 11) | (col & 2047). Per-bucket LDS staging; complete 16-entry
// chunks flushed as 16 consecutive dword stores (write amplification ~1).

__global__ __launch_bounds__(512) void k_bin2(const int* __restrict__ row,
                                              const int* __restrict__ col,
                                              const int* __restrict__ counts,
                                              const int* __restrict__ bucketBase,
                                              unsigned* __restrict__ binned) {
    __shared__ unsigned stage[NB][CAP];  // ~47 KB
    __shared__ int scnt[NB];
    __shared__ int gcur[NB];
    int w = blockIdx.x;
    for (int i = threadIdx.x; i < NB; i += 512) {
        scnt[i] = 0;
        gcur[i] = bucketBase[i] + counts[i * NWG + w];
    }
    __syncthreads();
    const int4* col4 = (const int4*)(col + (long long)w * EPW);
    const int4* row4 = (const int4*)(row + (long long)w * EPW);
    const int nq = EPW / 4;  // 8000 int4s; round = 512 int4 = 2048 edges
    for (int q0 = 0; q0 < nq; q0 += 512) {
        int q = q0 + threadIdx.x;
        int4 c, r;
        bool ok = (q < nq);
        if (ok) { c = col4[q]; r = row4[q]; }
        if (ok) {
            int cc[4] = {c.x, c.y, c.z, c.w};
            int rr[4] = {r.x, r.y, r.z, r.w};
#pragma unroll
            for (int k = 0; k < 4; ++k) {
                int b = cc[k] >> BSH;
                unsigned v = ((unsigned)rr[k] << BSH) | (unsigned)(cc[k] & BMASK);
                int s = atomicAdd(&scnt[b], 1);
                if (s < CAP) stage[b][s] = v;
                else { int p = atomicAdd(&gcur[b], 1); binned[p] = v; }  // rare
            }
        }
        __syncthreads();
        for (int b = threadIdx.x; b < NB; b += 512) {
            int n = scnt[b]; if (n > CAP) n = CAP;
            if (n >= CHUNK) {
                int p = atomicAdd(&gcur[b], CHUNK);
#pragma unroll
                for (int t = 0; t < CHUNK; ++t) binned[p + t] = stage[b][t];
                int rem = n - CHUNK;
                for (int t = 0; t < rem; ++t) stage[b][t] = stage[b][CHUNK + t];
                scnt[b] = rem;
            } else {
                scnt[b] = n;
            }
        }
        __syncthreads();
    }
    // tail: flush partial chunks
    for (int b = threadIdx.x; b < NB; b += 512) {
        int n = scnt[b]; if (n > CAP) n = CAP;
        if (n > 0) {
            int p = atomicAdd(&gcur[b], n);
            for (int t = 0; t < n; ++t) binned[p + t] = stage[b][t];
        }
    }
}

// ---------- build D (fused): histogram + scan -> ptr, dis; then scatter ------

__global__ __launch_bounds__(512) void k_sort(const unsigned* __restrict__ binned,
                                              const int* __restrict__ bucketBase,
                                              int* __restrict__ ptr,
                                              float* __restrict__ dis,
                                              int* __restrict__ sortedRow) {
    __shared__ int cnt[BNODES];  // 8 KB: histogram, then cursors
    __shared__ int tsum[512];
    int b = blockIdx.x, t = threadIdx.x;
    for (int i = t; i < BNODES; i += 512) cnt[i] = 0;
    __syncthreads();
    int i0 = bucketBase[b], i1 = bucketBase[b + 1];
    int i = i0 + t;
    for (; i + 3584 < i1; i += 4096) {
        unsigned v0 = binned[i],        v1 = binned[i +  512];
        unsigned v2 = binned[i + 1024], v3 = binned[i + 1536];
        unsigned v4 = binned[i + 2048], v5 = binned[i + 2560];
        unsigned v6 = binned[i + 3072], v7 = binned[i + 3584];
        atomicAdd(&cnt[v0 & BMASK], 1);
        atomicAdd(&cnt[v1 & BMASK], 1);
        atomicAdd(&cnt[v2 & BMASK], 1);
        atomicAdd(&cnt[v3 & BMASK], 1);
        atomicAdd(&cnt[v4 & BMASK], 1);
        atomicAdd(&cnt[v5 & BMASK], 1);
        atomicAdd(&cnt[v6 & BMASK], 1);
        atomicAdd(&cnt[v7 & BMASK], 1);
    }
    for (; i < i1; i += 512) atomicAdd(&cnt[binned[i] & BMASK], 1);
    __syncthreads();
    int s0 = cnt[t * 4], s1 = cnt[t * 4 + 1], s2 = cnt[t * 4 + 2], s3 = cnt[t * 4 + 3];
    int tot = s0 + s1 + s2 + s3;
    tsum[t] = tot;
    __syncthreads();
    for (int off = 1; off < 512; off <<= 1) {
        int x = (t >= off) ? tsum[t - off] : 0;
        __syncthreads();
        tsum[t] += x;
        __syncthreads();
    }
    int base = bucketBase[b] + tsum[t] - tot;  // exclusive start for node t*4
    int n0 = (b << BSH) + t * 4;
    if (n0 < NN)     { ptr[n0]     = base;                dis[n0]     = rsqrtf((float)(s0 + 1)); }
    if (n0 + 1 < NN) { ptr[n0 + 1] = base + s0;           dis[n0 + 1] = rsqrtf((float)(s1 + 1)); }
    if (n0 + 2 < NN) { ptr[n0 + 2] = base + s0 + s1;      dis[n0 + 2] = rsqrtf((float)(s2 + 1)); }
    if (n0 + 3 < NN) { ptr[n0 + 3] = base + s0 + s1 + s2; dis[n0 + 3] = rsqrtf((float)(s3 + 1)); }
    __syncthreads();
    // reuse cnt[] as running cursors
    cnt[t * 4]     = base;
    cnt[t * 4 + 1] = base + s0;
    cnt[t * 4 + 2] = base + s0 + s1;
    cnt[t * 4 + 3] = base + s0 + s1 + s2;
    __syncthreads();
    i = i0 + t;
    for (; i + 3584 < i1; i += 4096) {
        unsigned v0 = binned[i],        v1 = binned[i +  512];
        unsigned v2 = binned[i + 1024], v3 = binned[i + 1536];
        unsigned v4 = binned[i + 2048], v5 = binned[i + 2560];
        unsigned v6 = binned[i + 3072], v7 = binned[i + 3584];
        int p0 = atomicAdd(&cnt[v0 & BMASK], 1);
        int p1 = atomicAdd(&cnt[v1 & BMASK], 1);
        int p2 = atomicAdd(&cnt[v2 & BMASK], 1);
        int p3 = atomicAdd(&cnt[v3 & BMASK], 1);
        int p4 = atomicAdd(&cnt[v4 & BMASK], 1);
        int p5 = atomicAdd(&cnt[v5 & BMASK], 1);
        int p6 = atomicAdd(&cnt[v6 & BMASK], 1);
        int p7 = atomicAdd(&cnt[v7 & BMASK], 1);
        sortedRow[p0] = (int)(v0 >> BSH);
        sortedRow[p1] = (int)(v1 >> BSH);
        sortedRow[p2] = (int)(v2 >> BSH);
        sortedRow[p3] = (int)(v3 >> BSH);
        sortedRow[p4] = (int)(v4 >> BSH);
        sortedRow[p5] = (int)(v5 >> BSH);
        sortedRow[p6] = (int)(v6 >> BSH);
        sortedRow[p7] = (int)(v7 >> BSH);
    }
    for (; i < i1; i += 512) {
        unsigned v = binned[i];
        int pos = atomicAdd(&cnt[v & BMASK], 1);
        sortedRow[pos] = (int)(v >> BSH);
    }
}

// ---------- layer 1 linear: g1 = (x @ W1) * dis, LDS-staged coalesced x ------

__global__ __launch_bounds__(256) void k_lin1(const float* __restrict__ x,
                                              const float* __restrict__ W1,
                                              const float* __restrict__ dis,
                                              float* __restrict__ g1) {
    __shared__ float w[144];   // 9x16
    __shared__ float xs[2304]; // 256 nodes x 9 feats
    int t = threadIdx.x;
    if (t < 144) w[t] = W1[t];
    long long f4base = (long long)blockIdx.x * 576;  // block tile = 576 float4
    const float4* xv = (const float4*)x;
#pragma unroll
    for (int i = 0; i < 3; ++i) {
        int idx = t + i * 256;
        if (idx < 576 && f4base + idx < (long long)NN * 9 / 4)
            ((float4*)xs)[idx] = xv[f4base + idx];
    }
    __syncthreads();
    int n = blockIdx.x * 256 + t;
    if (n >= NN) return;
    float xvr[9];
#pragma unroll
    for (int k = 0; k < 9; ++k) xvr[k] = xs[t * 9 + k];
    float d = dis[n];
    float o[16];
#pragma unroll
    for (int j = 0; j < 16; ++j) {
        float acc = 0.f;
#pragma unroll
        for (int k = 0; k < 9; ++k) acc = fmaf(xvr[k], w[k * 16 + j], acc);
        o[j] = acc * d;
    }
    float4* dst = (float4*)(g1 + (long long)n * 16);
    dst[0] = make_float4(o[0], o[1], o[2], o[3]);
    dst[1] = make_float4(o[4], o[5], o[6], o[7]);
    dst[2] = make_float4(o[8], o[9], o[10], o[11]);
    dst[3] = make_float4(o[12], o[13], o[14], o[15]);
}

// ---------- fused pulls (proven round-8 form, untouched) ----------
// MODE 0: writeout fuses layer-2 linear: g2 = (relu(dis*acc + b1) @ W2pad) * dis
// MODE 1: writeout fuses final projection: out[n] = sum_j (dis*acc + b2)_j Wf_j + bf

template <int MODE>
__global__ void k_pull_f(const int* __restrict__ ptr, const int* __restrict__ sortedRow,
                         const float* __restrict__ dis, const float* __restrict__ g,
                         const float* __restrict__ p0, const float* __restrict__ p1,
                         const float* __restrict__ p2, float* __restrict__ dst) {
    __shared__ float w2s[256];  // MODE0: W2 padded [16][16]
    __shared__ float c16[16];   // MODE0: b1 | MODE1: b2 padded
    __shared__ float wf16[16];  // MODE1: Wf padded
    __shared__ float bfs;
    if (MODE == 0) {
        if (threadIdx.x < 256) {
            int k = threadIdx.x >> 4, j = threadIdx.x & 15;
            w2s[threadIdx.x] = (j < 10) ? p1[k * 10 + j] : 0.f;  // p1 = W2
        }
        if (threadIdx.x < 16) c16[threadIdx.x] = p0[threadIdx.x];  // p0 = b1 (16)
    } else {
        if (threadIdx.x < 16) {
            c16[threadIdx.x]  = (threadIdx.x < 10) ? p0[threadIdx.x] : 0.f;  // b2
            wf16[threadIdx.x] = (threadIdx.x < 10) ? p1[threadIdx.x] : 0.f;  // Wf
        }
        if (threadIdx.x == 0) bfs = p2[0];
    }
    __syncthreads();

    int grp = threadIdx.x >> 4;
    int j = threadIdx.x & 15;
    int n = blockIdx.x * 16 + grp;
    if (n >= NN) return;
    int e0 = ptr[n], e1 = ptr[n + 1];
    float acc = g[(long long)n * 16 + j];  // self-loop term
    int e = e0;
    for (; e + 16 <= e1; e += 16) {
        int r[16];
#pragma unroll
        for (int k = 0; k < 16; ++k) r[k] = sortedRow[e + k];
        float v[16];
#pragma unroll
        for (int k = 0; k < 16; ++k) v[k] = g[(long long)r[k] * 16 + j];
        float s0 = ((v[0] + v[1]) + (v[2] + v[3])) + ((v[4] + v[5]) + (v[6] + v[7]));
        float s1 = ((v[8] + v[9]) + (v[10] + v[11])) + ((v[12] + v[13]) + (v[14] + v[15]));
        acc += s0 + s1;
    }
    for (; e + 4 <= e1; e += 4) {
        int r0 = sortedRow[e + 0], r1 = sortedRow[e + 1];
        int r2 = sortedRow[e + 2], r3 = sortedRow[e + 3];
        float v0 = g[(long long)r0 * 16 + j];
        float v1 = g[(long long)r1 * 16 + j];
        float v2 = g[(long long)r2 * 16 + j];
        float v3 = g[(long long)r3 * 16 + j];
        acc += (v0 + v1) + (v2 + v3);
    }
    for (; e < e1; ++e)
        acc += g[(long long)sortedRow[e] * 16 + j];

    float d = dis[n];
    float val = d * acc;
    if (MODE == 0) {
        float hv = fmaxf(val + c16[j], 0.f);
        float o = 0.f;
#pragma unroll
        for (int k = 0; k < 16; ++k)
            o = fmaf(__shfl(hv, k, 16), w2s[k * 16 + j], o);
        dst[(long long)n * 16 + j] = o * d;
    } else {
        float t = (val + c16[j]) * wf16[j];
#pragma unroll
        for (int m = 8; m >= 1; m >>= 1) t += __shfl_xor(t, m, 16);
        if (j == 0) dst[n] = t + bfs;
    }
}

extern "C" void kernel_launch(void* const* d_in, const int* in_sizes, int n_in,
                              void* d_out, int out_size, void* d_ws, size_t ws_size,
                              hipStream_t stream) {
    const float* x  = (const float*)d_in[0];
    const int*   ei = (const int*)d_in[1];
    const float* W1 = (const float*)d_in[2];
    const float* b1 = (const float*)d_in[3];
    const float* W2 = (const float*)d_in[4];
    const float* b2 = (const float*)d_in[5];
    const float* Wf = (const float*)d_in[6];
    const float* bf = (const float*)d_in[7];
    float* out = (float*)d_out;

    const int* row = ei;
    const int* col = ei + NE;

    char* ws = (char*)d_ws;
    size_t off = 0;
    auto alloc = [&](size_t bytes) -> void* {
        void* p = ws + off;
        off += (bytes + 255) & ~255ULL;
        return p;
    };
    int* counts      = (int*)alloc((size_t)NB * NWG * 4);   // ~1 MB
    int* bucketTotal = (int*)alloc((size_t)NB * 4);
    int* bucketBase  = (int*)alloc((size_t)(NB + 1) * 4);
    int* ptr         = (int*)alloc((size_t)(NN + 1) * 4);
    float* dis       = (float*)alloc((size_t)NN * 4);
    unsigned* binned = (unsigned*)alloc((size_t)NE * 4);    // 64 MB; reused as g2
    int* sortedRow   = (int*)alloc((size_t)NE * 4);         // 64 MB
    float* g1        = (float*)alloc((size_t)NN * 16 * 4);  // 64 MB

    float* g2 = (float*)binned;  // binned dead after k_sort

    const int TB = 256;
    const int nodeGrid = (NN + TB - 1) / TB;
    const int pullGrid = (NN + 15) / 16;

    k_count<<<NWG, 512, 0, stream>>>(col, counts);
    k_scan_wg<<<NB, 512, 0, stream>>>(counts, bucketTotal);
    k_scan_total<<<1, 512, 0, stream>>>(bucketTotal, bucketBase, ptr);
    k_bin2<<<NWG, 512, 0, stream>>>(row, col, counts, bucketBase, binned);
    k_sort<<<NB, 512, 0, stream>>>(binned, bucketBase, ptr, dis, sortedRow);

    k_lin1<<<nodeGrid, TB, 0, stream>>>(x, W1, dis, g1);
    k_pull_f<0><<<pullGrid, TB, 0, stream>>>(ptr, sortedRow, dis, g1, b1, W2, nullptr, g2);
    k_pull_f<1><<<pullGrid, TB, 0, stream>>>(ptr, sortedRow, dis, g2, b2, Wf, bf, out);
}